// Round 10
// baseline (254.590 us; speedup 1.0000x reference)
//
#include <hip/hip_runtime.h>

#define GFINE 128
#define GC 64
#define NCELLS (GC * GC * GC)   // 262144
#define CIN 32
#define COUT 64

typedef __attribute__((ext_vector_type(8))) short bf16x8;   // 8 bf16 (4 VGPR)
typedef __attribute__((ext_vector_type(4))) float f32x4;    // MFMA acc / nt loads

// round-to-nearest-even float -> bf16 bits
__device__ __forceinline__ short f2bf(float f) {
    union { float f; unsigned u; } v; v.f = f;
    unsigned r = v.u + 0x7fffu + ((v.u >> 16) & 1u);
    return (short)(r >> 16);
}

// workspace layout (tab needs no init — vacant slots masked by occ bits)
#define TAB_OFF   0u               // [NCELLS*8] int, 8 MB
#define OCC_OFF   8388608u         // [NCELLS] int, 1 MB: bit k = tap k occupied
#define CL_OFF    9437184u         // [<=NCELLS] int cellList: (occ8<<18)|cell
#define BS_OFF    10485760u        // [256] int block cell-counts
#define WSWZ_OFF  10489856u        // 32 KB bf16 swizzled weights

// ---- Kernel 1: setup — zero occ (1 MB) + blockSums, swizzle weights ----
__global__ __launch_bounds__(256) void setup_kernel(const float* __restrict__ w,
                                                    char* __restrict__ ws) {
    int bid = blockIdx.x, tid = threadIdx.x;
    if (bid < 256) {                       // zero occ: 65536 int4
        ((int4*)(ws + OCC_OFF))[bid * 256 + tid] = make_int4(0, 0, 0, 0);
    } else if (bid == 256) {               // zero blockSums: 256 ints
        if (tid < 64) ((int4*)(ws + BS_OFF))[tid] = make_int4(0, 0, 0, 0);
    } else {                               // weight swizzle: 8 blocks x 256 = 2048
        int t = (bid - 257) * 256 + tid;
        int lane = t & 63, cb = (t >> 6) & 3, k = t >> 8;
        bf16x8 o;
#pragma unroll
        for (int e = 0; e < 8; ++e)
            o[e] = f2bf(w[(k * CIN + ((lane >> 4) * 8 + e)) * COUT + cb * 16 + (lane & 15)]);
        ((bf16x8*)(ws + WSWZ_OFF))[t] = o;
    }
}

// ---- Kernel 2: scatter — tab + occ bits + first-setter block cell-counts ----
__global__ __launch_bounds__(256) void scatter_kernel(const int* __restrict__ pos,
                                                      int n, int* __restrict__ tab,
                                                      int* __restrict__ occ,
                                                      int* __restrict__ blockSums) {
    int i = blockIdx.x * blockDim.x + threadIdx.x;
    if (i >= n) return;
    int x = __builtin_nontemporal_load(pos + i * 3 + 0);
    int y = __builtin_nontemporal_load(pos + i * 3 + 1);
    int z = __builtin_nontemporal_load(pos + i * 3 + 2);
    int cell = ((x >> 1) * GC + (y >> 1)) * GC + (z >> 1);
    int k = ((x & 1) << 2) | ((y & 1) << 1) | (z & 1);
    tab[cell * 8 + k] = i;
    int old = atomicOr(&occ[cell], 1 << k);
    if (old == 0) atomicAdd(&blockSums[cell >> 10], 1);   // first setter counts cell
}

// ---- Kernel 3: fused scan(local cells) + scan(block sums) + compact ----
__global__ __launch_bounds__(256) void compact_kernel(
    const int* __restrict__ occ, const int* __restrict__ blockSums,
    int* __restrict__ cellList, float* __restrict__ out_pos) {
    __shared__ int lds[256], ldsb[256];
    int tid = threadIdx.x, bid = blockIdx.x;
    int4 o = ((const int4*)occ)[bid * 256 + tid];
    int c0 = (o.x != 0), c1 = (o.y != 0), c2 = (o.z != 0), c3 = (o.w != 0);
    int s = c0 + c1 + c2 + c3;
    lds[tid] = s;
    ldsb[tid] = blockSums[tid];
    __syncthreads();
    for (int off = 1; off < 256; off <<= 1) {
        int t  = (tid >= off) ? lds[tid - off]  : 0;
        int tb = (tid >= off) ? ldsb[tid - off] : 0;
        __syncthreads();
        lds[tid]  += t;
        ldsb[tid] += tb;
        __syncthreads();
    }
    int excl_block = bid ? ldsb[bid - 1] : 0;      // exclusive prefix of block sums
    int rank = excl_block + lds[tid] - s;          // this thread's 1st cell rank
    int cellBase = (bid * 256 + tid) * 4;
    int oc[4] = {o.x, o.y, o.z, o.w};
#pragma unroll
    for (int c = 0; c < 4; ++c) {
        if (oc[c]) {
            int cell = cellBase + c;
            cellList[rank] = cell | (oc[c] << 18);
            int cx = cell >> 12, cy = (cell >> 6) & 63, cz = cell & 63;
            __builtin_nontemporal_store(cx + 0.25f, out_pos + rank * 3 + 0);
            __builtin_nontemporal_store(cy + 0.25f, out_pos + rank * 3 + 1);
            __builtin_nontemporal_store(cz + 0.25f, out_pos + rank * 3 + 2);
            ++rank;
        }
    }
}

// ---- Kernel 4: MFMA gather-GEMM. One wave per 16 output cells.
// K=256 = 8 taps x 32 cin; A rows = cells; tap row-indices read as 2x int4
// from tab; vacant taps skipped via exec-masked branches; feature gather and
// output stores are nontemporal (single-use streams — don't evict L2/L3).
__global__ __launch_bounds__(256) void conv_kernel(
    const float* __restrict__ feat, const short* __restrict__ wswz,
    const int* __restrict__ tab, const int* __restrict__ cellList,
    int M, float* __restrict__ out_feat) {
    const int lane = threadIdx.x & 63;
    const int wv = threadIdx.x >> 6;
    const int base = (blockIdx.x * 4 + wv) * 16;
    if (base >= M) return;
    const int cslot = lane & 15;     // A-frag row  = cell slot
    const int tgrp  = lane >> 4;     // A-frag K-chunk (8 elems) = cin chunk

    int rank = base + cslot;
    if (rank >= M) rank = M - 1;                 // dup last cell; C-write masked
    int e = cellList[rank];
    int cell = e & 0x3FFFF;
    int occ8 = (e >> 18) & 0xFF;

    const int4* tp = (const int4*)(tab + cell * 8);
    int4 t0 = tp[0], t1 = tp[1];
    int rr[8] = {t0.x, t0.y, t0.z, t0.w, t1.x, t1.y, t1.z, t1.w};

    // Phase 1: gather hit taps' fp32 chunks (32B/lane), exec-masked, nt
    f32x4 u[8], v[8];
#pragma unroll
    for (int k = 0; k < 8; ++k) {
        if ((occ8 >> k) & 1) {
            const f32x4* fr = (const f32x4*)(feat + (size_t)rr[k] * CIN + tgrp * 8);
            u[k] = __builtin_nontemporal_load(fr);
            v[k] = __builtin_nontemporal_load(fr + 1);
        }
    }

    // Phase 2: masked convert + 32 MFMAs (4 cout-blocks x 8 K-steps)
    const bf16x8* wf = (const bf16x8*)wswz;
    f32x4 acc0 = {0.f, 0.f, 0.f, 0.f}, acc1 = acc0, acc2 = acc0, acc3 = acc0;
#pragma unroll
    for (int k = 0; k < 8; ++k) {
        bf16x8 a = {0, 0, 0, 0, 0, 0, 0, 0};
        if ((occ8 >> k) & 1) {
            a[0] = f2bf(u[k][0]); a[1] = f2bf(u[k][1]);
            a[2] = f2bf(u[k][2]); a[3] = f2bf(u[k][3]);
            a[4] = f2bf(v[k][0]); a[5] = f2bf(v[k][1]);
            a[6] = f2bf(v[k][2]); a[7] = f2bf(v[k][3]);
        }
        acc0 = __builtin_amdgcn_mfma_f32_16x16x32_bf16(a, wf[(k * 4 + 0) * 64 + lane], acc0, 0, 0, 0);
        acc1 = __builtin_amdgcn_mfma_f32_16x16x32_bf16(a, wf[(k * 4 + 1) * 64 + lane], acc1, 0, 0, 0);
        acc2 = __builtin_amdgcn_mfma_f32_16x16x32_bf16(a, wf[(k * 4 + 2) * 64 + lane], acc2, 0, 0, 0);
        acc3 = __builtin_amdgcn_mfma_f32_16x16x32_bf16(a, wf[(k * 4 + 3) * 64 + lane], acc3, 0, 0, 0);
    }

    // C-write: D row = tgrp*4+i (within tile), col = cslot; nt scalar stores
#pragma unroll
    for (int i = 0; i < 4; ++i) {
        int row = base + tgrp * 4 + i;
        if (row < M) {
            float* o = out_feat + (size_t)row * COUT + cslot;
            __builtin_nontemporal_store(acc0[i], o);
            __builtin_nontemporal_store(acc1[i], o + 16);
            __builtin_nontemporal_store(acc2[i], o + 32);
            __builtin_nontemporal_store(acc3[i], o + 48);
        }
    }
}

extern "C" void kernel_launch(void* const* d_in, const int* in_sizes, int n_in,
                              void* d_out, int out_size, void* d_ws, size_t ws_size,
                              hipStream_t stream) {
    const float* feat   = (const float*)d_in[0];
    const int*   pos    = (const int*)d_in[1];
    const float* weight = (const float*)d_in[2];
    int n = in_sizes[1] / 3;
    int M = out_size / 67;   // out_feat M*64 + out_pos M*3

    char* ws = (char*)d_ws;
    int*   tab       = (int*)(ws + TAB_OFF);
    int*   occ       = (int*)(ws + OCC_OFF);
    int*   cellList  = (int*)(ws + CL_OFF);
    int*   blockSums = (int*)(ws + BS_OFF);
    short* wswz      = (short*)(ws + WSWZ_OFF);

    float* out_feat = (float*)d_out;
    float* out_pos  = (float*)d_out + (size_t)M * COUT;

    setup_kernel<<<265, 256, 0, stream>>>(weight, ws);
    scatter_kernel<<<(n + 255) / 256, 256, 0, stream>>>(pos, n, tab, occ, blockSums);
    compact_kernel<<<256, 256, 0, stream>>>(occ, blockSums, cellList, out_pos);
    conv_kernel<<<(M + 63) / 64, 256, 0, stream>>>(feat, wswz, tab, cellList,
                                                   M, out_feat);
}

// Round 11
// 155.825 us; speedup vs baseline: 1.6338x; 1.6338x over previous
//
#include <hip/hip_runtime.h>

#define GFINE 128
#define GC 64
#define NCELLS (GC * GC * GC)   // 262144
#define CIN 32
#define COUT 64

typedef __attribute__((ext_vector_type(8))) short bf16x8;   // 8 bf16 (4 VGPR)
typedef __attribute__((ext_vector_type(4))) float f32x4;    // MFMA acc

// round-to-nearest-even float -> bf16 bits
__device__ __forceinline__ short f2bf(float f) {
    union { float f; unsigned u; } v; v.f = f;
    unsigned r = v.u + 0x7fffu + ((v.u >> 16) & 1u);
    return (short)(r >> 16);
}

// workspace layout (tab needs no init — vacant slots masked by occ bits)
#define TAB_OFF   0u               // [NCELLS*8] int, 8 MB
#define OCC_OFF   8388608u         // [NCELLS] int, 1 MB: bit k = tap k occupied
#define CL_OFF    9437184u         // [<=NCELLS] int cellList: (occ8<<18)|cell
#define BS_OFF    10485760u        // [256] int block cell-counts
#define WSWZ_OFF  10489856u        // 32 KB bf16 swizzled weights

// ---- Kernel 1: setup — zero occ (1 MB) + blockSums, swizzle weights ----
__global__ __launch_bounds__(256) void setup_kernel(const float* __restrict__ w,
                                                    char* __restrict__ ws) {
    int bid = blockIdx.x, tid = threadIdx.x;
    if (bid < 256) {                       // zero occ: 65536 int4
        ((int4*)(ws + OCC_OFF))[bid * 256 + tid] = make_int4(0, 0, 0, 0);
    } else if (bid == 256) {               // zero blockSums: 256 ints
        if (tid < 64) ((int4*)(ws + BS_OFF))[tid] = make_int4(0, 0, 0, 0);
    } else {                               // weight swizzle: 8 blocks x 256 = 2048
        int t = (bid - 257) * 256 + tid;
        int lane = t & 63, cb = (t >> 6) & 3, k = t >> 8;
        bf16x8 o;
#pragma unroll
        for (int e = 0; e < 8; ++e)
            o[e] = f2bf(w[(k * CIN + ((lane >> 4) * 8 + e)) * COUT + cb * 16 + (lane & 15)]);
        ((bf16x8*)(ws + WSWZ_OFF))[t] = o;
    }
}

// ---- Kernel 2: scatter — tab + occ bits + first-setter block cell-counts ----
__global__ __launch_bounds__(256) void scatter_kernel(const int* __restrict__ pos,
                                                      int n, int* __restrict__ tab,
                                                      int* __restrict__ occ,
                                                      int* __restrict__ blockSums) {
    int i = blockIdx.x * blockDim.x + threadIdx.x;
    if (i >= n) return;
    int x = pos[i * 3 + 0];
    int y = pos[i * 3 + 1];
    int z = pos[i * 3 + 2];
    int cell = ((x >> 1) * GC + (y >> 1)) * GC + (z >> 1);
    int k = ((x & 1) << 2) | ((y & 1) << 1) | (z & 1);
    tab[cell * 8 + k] = i;
    int old = atomicOr(&occ[cell], 1 << k);
    if (old == 0) atomicAdd(&blockSums[cell >> 10], 1);   // first setter counts cell
}

// ---- Kernel 3: fused scan(local cells) + scan(block sums) + compact ----
__global__ __launch_bounds__(256) void compact_kernel(
    const int* __restrict__ occ, const int* __restrict__ blockSums,
    int* __restrict__ cellList, float* __restrict__ out_pos) {
    __shared__ int lds[256], ldsb[256];
    int tid = threadIdx.x, bid = blockIdx.x;
    int4 o = ((const int4*)occ)[bid * 256 + tid];
    int c0 = (o.x != 0), c1 = (o.y != 0), c2 = (o.z != 0), c3 = (o.w != 0);
    int s = c0 + c1 + c2 + c3;
    lds[tid] = s;
    ldsb[tid] = blockSums[tid];
    __syncthreads();
    for (int off = 1; off < 256; off <<= 1) {
        int t  = (tid >= off) ? lds[tid - off]  : 0;
        int tb = (tid >= off) ? ldsb[tid - off] : 0;
        __syncthreads();
        lds[tid]  += t;
        ldsb[tid] += tb;
        __syncthreads();
    }
    int excl_block = bid ? ldsb[bid - 1] : 0;      // exclusive prefix of block sums
    int rank = excl_block + lds[tid] - s;          // this thread's 1st cell rank
    int cellBase = (bid * 256 + tid) * 4;
    int oc[4] = {o.x, o.y, o.z, o.w};
#pragma unroll
    for (int c = 0; c < 4; ++c) {
        if (oc[c]) {
            int cell = cellBase + c;
            cellList[rank] = cell | (oc[c] << 18);
            int cx = cell >> 12, cy = (cell >> 6) & 63, cz = cell & 63;
            out_pos[rank * 3 + 0] = cx + 0.25f;
            out_pos[rank * 3 + 1] = cy + 0.25f;
            out_pos[rank * 3 + 2] = cz + 0.25f;
            ++rank;
        }
    }
}

// ---- Kernel 4: MFMA gather-GEMM. One wave per 16 output cells.
// K=256 = 8 taps x 32 cin; A rows = cells; tap row-indices read as 2x int4
// from tab (coalesced); vacant taps skipped via exec-masked branches;
// plain cached loads (L2/L3 absorb gather re-reads — do NOT use nt here).
__global__ __launch_bounds__(256) void conv_kernel(
    const float* __restrict__ feat, const short* __restrict__ wswz,
    const int* __restrict__ tab, const int* __restrict__ cellList,
    int M, float* __restrict__ out_feat) {
    const int lane = threadIdx.x & 63;
    const int wv = threadIdx.x >> 6;
    const int base = (blockIdx.x * 4 + wv) * 16;
    if (base >= M) return;
    const int cslot = lane & 15;     // A-frag row  = cell slot
    const int tgrp  = lane >> 4;     // A-frag K-chunk (8 elems) = cin chunk

    int rank = base + cslot;
    if (rank >= M) rank = M - 1;                 // dup last cell; C-write masked
    int e = cellList[rank];
    int cell = e & 0x3FFFF;
    int occ8 = (e >> 18) & 0xFF;

    const int4* tp = (const int4*)(tab + cell * 8);
    int4 t0 = tp[0], t1 = tp[1];
    int rr[8] = {t0.x, t0.y, t0.z, t0.w, t1.x, t1.y, t1.z, t1.w};

    // Phase 1: gather hit taps' fp32 chunks (32B/lane), overlapped
    float4 u[8], v[8];
#pragma unroll
    for (int k = 0; k < 8; ++k) {
        if ((occ8 >> k) & 1) {
            const float4* fr = (const float4*)(feat + (size_t)rr[k] * CIN + tgrp * 8);
            u[k] = fr[0];
            v[k] = fr[1];
        }
    }

    // Phase 2: masked convert + 32 MFMAs (4 cout-blocks x 8 K-steps)
    const bf16x8* wf = (const bf16x8*)wswz;
    f32x4 acc0 = {0.f, 0.f, 0.f, 0.f}, acc1 = acc0, acc2 = acc0, acc3 = acc0;
#pragma unroll
    for (int k = 0; k < 8; ++k) {
        bf16x8 a = {0, 0, 0, 0, 0, 0, 0, 0};
        if ((occ8 >> k) & 1) {
            a[0] = f2bf(u[k].x); a[1] = f2bf(u[k].y);
            a[2] = f2bf(u[k].z); a[3] = f2bf(u[k].w);
            a[4] = f2bf(v[k].x); a[5] = f2bf(v[k].y);
            a[6] = f2bf(v[k].z); a[7] = f2bf(v[k].w);
        }
        acc0 = __builtin_amdgcn_mfma_f32_16x16x32_bf16(a, wf[(k * 4 + 0) * 64 + lane], acc0, 0, 0, 0);
        acc1 = __builtin_amdgcn_mfma_f32_16x16x32_bf16(a, wf[(k * 4 + 1) * 64 + lane], acc1, 0, 0, 0);
        acc2 = __builtin_amdgcn_mfma_f32_16x16x32_bf16(a, wf[(k * 4 + 2) * 64 + lane], acc2, 0, 0, 0);
        acc3 = __builtin_amdgcn_mfma_f32_16x16x32_bf16(a, wf[(k * 4 + 3) * 64 + lane], acc3, 0, 0, 0);
    }

    // C-write: D row = tgrp*4+i (within tile), col = cslot (within cout-block)
#pragma unroll
    for (int i = 0; i < 4; ++i) {
        int row = base + tgrp * 4 + i;
        if (row < M) {
            float* o = out_feat + (size_t)row * COUT + cslot;
            o[0]  = acc0[i];
            o[16] = acc1[i];
            o[32] = acc2[i];
            o[48] = acc3[i];
        }
    }
}

extern "C" void kernel_launch(void* const* d_in, const int* in_sizes, int n_in,
                              void* d_out, int out_size, void* d_ws, size_t ws_size,
                              hipStream_t stream) {
    const float* feat   = (const float*)d_in[0];
    const int*   pos    = (const int*)d_in[1];
    const float* weight = (const float*)d_in[2];
    int n = in_sizes[1] / 3;
    int M = out_size / 67;   // out_feat M*64 + out_pos M*3

    char* ws = (char*)d_ws;
    int*   tab       = (int*)(ws + TAB_OFF);
    int*   occ       = (int*)(ws + OCC_OFF);
    int*   cellList  = (int*)(ws + CL_OFF);
    int*   blockSums = (int*)(ws + BS_OFF);
    short* wswz      = (short*)(ws + WSWZ_OFF);

    float* out_feat = (float*)d_out;
    float* out_pos  = (float*)d_out + (size_t)M * COUT;

    setup_kernel<<<265, 256, 0, stream>>>(weight, ws);
    scatter_kernel<<<(n + 255) / 256, 256, 0, stream>>>(pos, n, tab, occ, blockSums);
    compact_kernel<<<256, 256, 0, stream>>>(occ, blockSums, cellList, out_pos);
    conv_kernel<<<(M + 63) / 64, 256, 0, stream>>>(feat, wswz, tab, cellList,
                                                   M, out_feat);
}

// Round 12
// 58.993 us; speedup vs baseline: 4.3156x; 2.6414x over previous
//
#include <hip/hip_runtime.h>

#define GFINE 128
#define GC 64
#define NCELLS (GC * GC * GC)   // 262144
#define CIN 32
#define COUT 64

typedef __attribute__((ext_vector_type(8))) short bf16x8;   // 8 bf16 (4 VGPR)
typedef __attribute__((ext_vector_type(4))) float f32x4;    // MFMA acc

// round-to-nearest-even float -> bf16 bits
__device__ __forceinline__ short f2bf(float f) {
    union { float f; unsigned u; } v; v.f = f;
    unsigned r = v.u + 0x7fffu + ((v.u >> 16) & 1u);
    return (short)(r >> 16);
}

// workspace layout (tab needs no init — vacant slots masked by occ bits)
#define TAB_OFF   0u               // [NCELLS*8] int, 8 MB
#define OCC_OFF   8388608u         // [NCELLS] int, 1 MB: bit k = tap k occupied
#define CL_OFF    9437184u         // [<=NCELLS] int cellList: (occ8<<18)|cell
#define BS_OFF    10485760u        // [256] int block cell-counts
#define WSWZ_OFF  10489856u        // 32 KB bf16 swizzled weights

// ---- Kernel 1: setup — zero occ (1 MB), swizzle weights ----
__global__ __launch_bounds__(256) void setup_kernel(const float* __restrict__ w,
                                                    char* __restrict__ ws) {
    int bid = blockIdx.x, tid = threadIdx.x;
    if (bid < 256) {                       // zero occ: 65536 int4
        ((int4*)(ws + OCC_OFF))[bid * 256 + tid] = make_int4(0, 0, 0, 0);
    } else {                               // weight swizzle: 8 blocks x 256 = 2048
        int t = (bid - 256) * 256 + tid;
        int lane = t & 63, cb = (t >> 6) & 3, k = t >> 8;
        bf16x8 o;
#pragma unroll
        for (int e = 0; e < 8; ++e)
            o[e] = f2bf(w[(k * CIN + ((lane >> 4) * 8 + e)) * COUT + cb * 16 + (lane & 15)]);
        ((bf16x8*)(ws + WSWZ_OFF))[t] = o;
    }
}

// ---- Kernel 2: scatter — tab + occ bits (fire-and-forget atomics only) ----
__global__ __launch_bounds__(256) void scatter_kernel(const int* __restrict__ pos,
                                                      int n, int* __restrict__ tab,
                                                      int* __restrict__ occ) {
    int i = blockIdx.x * blockDim.x + threadIdx.x;
    if (i >= n) return;
    int x = pos[i * 3 + 0];
    int y = pos[i * 3 + 1];
    int z = pos[i * 3 + 2];
    int cell = ((x >> 1) * GC + (y >> 1)) * GC + (z >> 1);
    int k = ((x & 1) << 2) | ((y & 1) << 1) | (z & 1);
    tab[cell * 8 + k] = i;
    atomicOr(&occ[cell], 1 << k);        // no return value read -> no round-trip
}

// ---- Kernel 3: per-1024-cell block occupied-cell counts (dense reduce) ----
__global__ __launch_bounds__(256) void sum_kernel(const int* __restrict__ occ,
                                                  int* __restrict__ blockSums) {
    __shared__ int lds[256];
    int tid = threadIdx.x, bid = blockIdx.x;
    int4 o = ((const int4*)occ)[bid * 256 + tid];
    lds[tid] = (o.x != 0) + (o.y != 0) + (o.z != 0) + (o.w != 0);
    __syncthreads();
    for (int off = 128; off > 0; off >>= 1) {
        if (tid < off) lds[tid] += lds[tid + off];
        __syncthreads();
    }
    if (tid == 0) blockSums[bid] = lds[0];
}

// ---- Kernel 4: fused scan(local cells) + scan(block sums) + compact ----
__global__ __launch_bounds__(256) void compact_kernel(
    const int* __restrict__ occ, const int* __restrict__ blockSums,
    int* __restrict__ cellList, float* __restrict__ out_pos) {
    __shared__ int lds[256], ldsb[256];
    int tid = threadIdx.x, bid = blockIdx.x;
    int4 o = ((const int4*)occ)[bid * 256 + tid];
    int c0 = (o.x != 0), c1 = (o.y != 0), c2 = (o.z != 0), c3 = (o.w != 0);
    int s = c0 + c1 + c2 + c3;
    lds[tid] = s;
    ldsb[tid] = blockSums[tid];
    __syncthreads();
    for (int off = 1; off < 256; off <<= 1) {
        int t  = (tid >= off) ? lds[tid - off]  : 0;
        int tb = (tid >= off) ? ldsb[tid - off] : 0;
        __syncthreads();
        lds[tid]  += t;
        ldsb[tid] += tb;
        __syncthreads();
    }
    int excl_block = bid ? ldsb[bid - 1] : 0;      // exclusive prefix of block sums
    int rank = excl_block + lds[tid] - s;          // this thread's 1st cell rank
    int cellBase = (bid * 256 + tid) * 4;
    int oc[4] = {o.x, o.y, o.z, o.w};
#pragma unroll
    for (int c = 0; c < 4; ++c) {
        if (oc[c]) {
            int cell = cellBase + c;
            cellList[rank] = cell | (oc[c] << 18);
            int cx = cell >> 12, cy = (cell >> 6) & 63, cz = cell & 63;
            out_pos[rank * 3 + 0] = cx + 0.25f;
            out_pos[rank * 3 + 1] = cy + 0.25f;
            out_pos[rank * 3 + 2] = cz + 0.25f;
            ++rank;
        }
    }
}

// ---- Kernel 5: MFMA gather-GEMM. One wave per 16 output cells.
// K=256 = 8 taps x 32 cin; A rows = cells; tap row-indices read as 2x int4
// from tab (coalesced); vacant taps skipped via exec-masked branches;
// plain cached loads (L2/L3 absorb gather re-reads — do NOT use nt here).
__global__ __launch_bounds__(256) void conv_kernel(
    const float* __restrict__ feat, const short* __restrict__ wswz,
    const int* __restrict__ tab, const int* __restrict__ cellList,
    int M, float* __restrict__ out_feat) {
    const int lane = threadIdx.x & 63;
    const int wv = threadIdx.x >> 6;
    const int base = (blockIdx.x * 4 + wv) * 16;
    if (base >= M) return;
    const int cslot = lane & 15;     // A-frag row  = cell slot
    const int tgrp  = lane >> 4;     // A-frag K-chunk (8 elems) = cin chunk

    int rank = base + cslot;
    if (rank >= M) rank = M - 1;                 // dup last cell; C-write masked
    int e = cellList[rank];
    int cell = e & 0x3FFFF;
    int occ8 = (e >> 18) & 0xFF;

    const int4* tp = (const int4*)(tab + cell * 8);
    int4 t0 = tp[0], t1 = tp[1];
    int rr[8] = {t0.x, t0.y, t0.z, t0.w, t1.x, t1.y, t1.z, t1.w};

    // Phase 1: gather hit taps' fp32 chunks (32B/lane), overlapped
    float4 u[8], v[8];
#pragma unroll
    for (int k = 0; k < 8; ++k) {
        if ((occ8 >> k) & 1) {
            const float4* fr = (const float4*)(feat + (size_t)rr[k] * CIN + tgrp * 8);
            u[k] = fr[0];
            v[k] = fr[1];
        }
    }

    // Phase 2: masked convert + 32 MFMAs (4 cout-blocks x 8 K-steps)
    const bf16x8* wf = (const bf16x8*)wswz;
    f32x4 acc0 = {0.f, 0.f, 0.f, 0.f}, acc1 = acc0, acc2 = acc0, acc3 = acc0;
#pragma unroll
    for (int k = 0; k < 8; ++k) {
        bf16x8 a = {0, 0, 0, 0, 0, 0, 0, 0};
        if ((occ8 >> k) & 1) {
            a[0] = f2bf(u[k].x); a[1] = f2bf(u[k].y);
            a[2] = f2bf(u[k].z); a[3] = f2bf(u[k].w);
            a[4] = f2bf(v[k].x); a[5] = f2bf(v[k].y);
            a[6] = f2bf(v[k].z); a[7] = f2bf(v[k].w);
        }
        acc0 = __builtin_amdgcn_mfma_f32_16x16x32_bf16(a, wf[(k * 4 + 0) * 64 + lane], acc0, 0, 0, 0);
        acc1 = __builtin_amdgcn_mfma_f32_16x16x32_bf16(a, wf[(k * 4 + 1) * 64 + lane], acc1, 0, 0, 0);
        acc2 = __builtin_amdgcn_mfma_f32_16x16x32_bf16(a, wf[(k * 4 + 2) * 64 + lane], acc2, 0, 0, 0);
        acc3 = __builtin_amdgcn_mfma_f32_16x16x32_bf16(a, wf[(k * 4 + 3) * 64 + lane], acc3, 0, 0, 0);
    }

    // C-write: D row = tgrp*4+i (within tile), col = cslot (within cout-block)
#pragma unroll
    for (int i = 0; i < 4; ++i) {
        int row = base + tgrp * 4 + i;
        if (row < M) {
            float* o = out_feat + (size_t)row * COUT + cslot;
            o[0]  = acc0[i];
            o[16] = acc1[i];
            o[32] = acc2[i];
            o[48] = acc3[i];
        }
    }
}

extern "C" void kernel_launch(void* const* d_in, const int* in_sizes, int n_in,
                              void* d_out, int out_size, void* d_ws, size_t ws_size,
                              hipStream_t stream) {
    const float* feat   = (const float*)d_in[0];
    const int*   pos    = (const int*)d_in[1];
    const float* weight = (const float*)d_in[2];
    int n = in_sizes[1] / 3;
    int M = out_size / 67;   // out_feat M*64 + out_pos M*3

    char* ws = (char*)d_ws;
    int*   tab       = (int*)(ws + TAB_OFF);
    int*   occ       = (int*)(ws + OCC_OFF);
    int*   cellList  = (int*)(ws + CL_OFF);
    int*   blockSums = (int*)(ws + BS_OFF);
    short* wswz      = (short*)(ws + WSWZ_OFF);

    float* out_feat = (float*)d_out;
    float* out_pos  = (float*)d_out + (size_t)M * COUT;

    setup_kernel<<<264, 256, 0, stream>>>(weight, ws);
    scatter_kernel<<<(n + 255) / 256, 256, 0, stream>>>(pos, n, tab, occ);
    sum_kernel<<<256, 256, 0, stream>>>(occ, blockSums);
    compact_kernel<<<256, 256, 0, stream>>>(occ, blockSums, cellList, out_pos);
    conv_kernel<<<(M + 63) / 64, 256, 0, stream>>>(feat, wswz, tab, cellList,
                                                   M, out_feat);
}